// Round 1
// baseline (24277.655 us; speedup 1.0000x reference)
//
#include <hip/hip_runtime.h>
#include <hip/hip_bf16.h>

#define B_  32
#define TS_ 64
#define TD_ 63
#define E_  256
#define U_  1024
#define G_  4096   // 4*U
#define VT_ 32000

typedef __attribute__((ext_vector_type(8))) short short8;
typedef __attribute__((ext_vector_type(4))) float floatx4;

__device__ __forceinline__ float sigf(float x){ return 1.0f/(1.0f+__expf(-x)); }
__device__ __forceinline__ float tanh_fast(float x){ return 2.0f/(1.0f+__expf(-2.0f*x)) - 1.0f; }
__device__ __forceinline__ unsigned short f2bf(float x){
  unsigned u = __float_as_uint(x);
  u += 0x7FFFu + ((u>>16)&1u);
  return (unsigned short)(u>>16);
}

// ---------------- zero init ----------------
__global__ void zero_kernel(float4* __restrict__ p, int n4){
  int i = blockIdx.x*256 + threadIdx.x;
  if(i < n4) p[i] = make_float4(0.f,0.f,0.f,0.f);
}

// ---------------- generic row-gather GEMM (fp32) ----------------
// C[m][n] = bias[n] + sum_k Arow(m)[k] * Bw[k*N + n]
// Arow(m) = tokens ? &Atab[tokens[(m%32)*T + m/32] * K] : &Atab[m*K]
// grid: (N/256, M/16), block 256
__global__ __launch_bounds__(256) void gemm_rows(
    const float* __restrict__ Atab, const int* __restrict__ tokens, int T,
    const float* __restrict__ Bw, const float* __restrict__ bias,
    float* __restrict__ C, int N, int K)
{
  __shared__ float as[64*20];   // [kk][mm] with stride 20 (16B-aligned rows)
  int tid = threadIdx.x;
  int n  = blockIdx.x*256 + tid;
  int m0 = blockIdx.y*16;
  float acc[16];
  #pragma unroll
  for(int r=0;r<16;r++) acc[r]=0.f;

  for(int kc=0; kc<K; kc+=64){
    __syncthreads();
    for(int i=tid; i<16*64; i+=256){
      int mm = i>>6, kk = i&63;
      int m = m0 + mm;
      const float* arow;
      if(tokens){
        int b = m & 31, t = m >> 5;
        arow = Atab + (size_t)tokens[b*T + t]*K;
      } else {
        arow = Atab + (size_t)m*K;
      }
      as[kk*20 + mm] = arow[kc + kk];
    }
    __syncthreads();
    for(int kk=0; kk<64; kk++){
      float bv = Bw[(size_t)(kc+kk)*N + n];
      const float4* ap = (const float4*)(as + kk*20);
      float4 a0 = ap[0], a1 = ap[1], a2 = ap[2], a3 = ap[3];
      acc[0]  += a0.x*bv; acc[1]  += a0.y*bv; acc[2]  += a0.z*bv; acc[3]  += a0.w*bv;
      acc[4]  += a1.x*bv; acc[5]  += a1.y*bv; acc[6]  += a1.z*bv; acc[7]  += a1.w*bv;
      acc[8]  += a2.x*bv; acc[9]  += a2.y*bv; acc[10] += a2.z*bv; acc[11] += a2.w*bv;
      acc[12] += a3.x*bv; acc[13] += a3.y*bv; acc[14] += a3.z*bv; acc[15] += a3.w*bv;
    }
  }
  float bv = bias ? bias[n] : 0.f;
  #pragma unroll
  for(int r=0;r<16;r++)
    C[(size_t)(m0+r)*N + n] = acc[r] + bv;
}

// ---------------- encoder LSTM step ----------------
// grid: 256 (u-tiles of 4), block 256. z = Xe_t + hprev @ Wh ; gates ; c,h update
__global__ __launch_bounds__(256) void enc_step(
    const float* __restrict__ Xe_t, const float* __restrict__ Wh,
    const float* __restrict__ hprev, float* __restrict__ c,
    float* __restrict__ mem_t)
{
  int tid = threadIdx.x;
  int u0 = blockIdx.x*4;
  int jc = tid & 15, bh = tid >> 4;          // jc: gate*4+ul, bh: 0..15
  int j = (jc>>2)*U_ + u0 + (jc&3);
  float acc0 = Xe_t[bh*G_ + j];
  float acc1 = Xe_t[(bh+16)*G_ + j];
  const float* wcol = Wh + j;
  const float* h0p = hprev + bh*U_;
  const float* h1p = hprev + (bh+16)*U_;
  #pragma unroll 4
  for(int k=0;k<U_;k++){
    float w = wcol[(size_t)k*G_];
    acc0 += h0p[k]*w;
    acc1 += h1p[k]*w;
  }
  __shared__ float zbuf[32][17];
  zbuf[bh][jc]=acc0; zbuf[bh+16][jc]=acc1;
  __syncthreads();
  if(tid<128){
    int b = tid>>2, ul = tid&3;
    int u = u0+ul;
    float iz=zbuf[b][ul], fz=zbuf[b][4+ul], gz=zbuf[b][8+ul], oz=zbuf[b][12+ul];
    float cn = sigf(fz)*c[b*U_+u] + sigf(iz)*tanh_fast(gz);
    float hn = sigf(oz)*tanh_fast(cn);
    c[b*U_+u]=cn;
    mem_t[b*U_+u]=hn;
  }
}

// ---------------- decoder LSTM step ----------------
// z = Xd_t + hin @ Wh + aprev @ Wxa ; gates ; c in-place, h -> hout
__global__ __launch_bounds__(256) void dec_step(
    const float* __restrict__ Xd_t, const float* __restrict__ Wh,
    const float* __restrict__ Wxa, const float* __restrict__ hin,
    const float* __restrict__ aprev, float* __restrict__ c,
    float* __restrict__ hout)
{
  int tid = threadIdx.x;
  int u0 = blockIdx.x*4;
  int jc = tid & 15, bh = tid >> 4;
  int j = (jc>>2)*U_ + u0 + (jc&3);
  float acc0 = Xd_t[bh*G_ + j];
  float acc1 = Xd_t[(bh+16)*G_ + j];
  const float* w1 = Wh + j;
  const float* w2 = Wxa + j;
  const float* h0p = hin + bh*U_;
  const float* h1p = hin + (bh+16)*U_;
  const float* a0p = aprev + bh*U_;
  const float* a1p = aprev + (bh+16)*U_;
  #pragma unroll 4
  for(int k=0;k<U_;k++){
    float wa_ = w1[(size_t)k*G_];
    float wb_ = w2[(size_t)k*G_];
    acc0 += h0p[k]*wa_ + a0p[k]*wb_;
    acc1 += h1p[k]*wa_ + a1p[k]*wb_;
  }
  __shared__ float zbuf[32][17];
  zbuf[bh][jc]=acc0; zbuf[bh+16][jc]=acc1;
  __syncthreads();
  if(tid<128){
    int b = tid>>2, ul = tid&3;
    int u = u0+ul;
    float iz=zbuf[b][ul], fz=zbuf[b][4+ul], gz=zbuf[b][8+ul], oz=zbuf[b][12+ul];
    float cn = sigf(fz)*c[b*U_+u] + sigf(iz)*tanh_fast(gz);
    float hn = sigf(oz)*tanh_fast(cn);
    c[b*U_+u]=cn;
    hout[b*U_+u]=hn;
  }
}

// ---------------- attention: scores + softmax + context ----------------
// grid: (8 u-chunks of 128, 32 batch), block 256
__global__ __launch_bounds__(256) void attn_ctx(
    const float* __restrict__ hcur, const float* __restrict__ keys,
    const float* __restrict__ memory, float* __restrict__ ctx)
{
  int b = blockIdx.y, uq = blockIdx.x;
  __shared__ float hs[1024];
  __shared__ float sc[64];
  __shared__ float al[64];
  int tid = threadIdx.x;
  for(int i=tid;i<1024;i+=256) hs[i] = hcur[b*U_+i];
  __syncthreads();
  int w = tid>>6, lane = tid&63;
  for(int si=0; si<16; si++){
    int s = w*16 + si;
    const float* krow = keys + ((size_t)s*B_ + b)*U_;
    float p = 0.f;
    for(int kk=lane; kk<1024; kk+=64) p += hs[kk]*krow[kk];
    for(int off=32; off; off>>=1) p += __shfl_down(p, off);
    if(lane==0) sc[s] = p;
  }
  __syncthreads();
  if(tid<64){
    float v = sc[tid];
    float mx = v;
    for(int off=32; off; off>>=1) mx = fmaxf(mx, __shfl_down(mx, off));
    mx = __shfl(mx, 0);
    float e = __expf(v - mx);
    float sm = e;
    for(int off=32; off; off>>=1) sm += __shfl_down(sm, off);
    sm = __shfl(sm, 0);
    al[tid] = e/sm;
  }
  __syncthreads();
  if(tid<128){
    int u = uq*128 + tid;
    float acc = 0.f;
    for(int s=0;s<64;s++) acc += al[s]*memory[((size_t)s*B_ + b)*U_ + u];
    ctx[b*U_+u] = acc;
  }
}

// ---------------- attention projection: attn = [h|ctx] @ Wa ----------------
// grid: (64 n-tiles of 16, 4 k-chunks of 512), block 256, atomic K-split
__global__ __launch_bounds__(256) void attn_proj(
    const float* __restrict__ hcur, const float* __restrict__ ctx,
    const float* __restrict__ Wa, float* __restrict__ attn_out)
{
  int tid = threadIdx.x;
  int nl = tid&15, bh = tid>>4;
  int n = blockIdx.x*16 + nl;
  int kq = blockIdx.y;
  const float* Asrc = (kq<2) ? hcur : ctx;
  int k0 = (kq&1)*512;
  const float* wcol = Wa + (size_t)(kq*512)*U_ + n;
  const float* a0p = Asrc + bh*U_ + k0;
  const float* a1p = Asrc + (bh+16)*U_ + k0;
  float acc0=0.f, acc1=0.f;
  #pragma unroll 4
  for(int k=0;k<512;k++){
    float wv = wcol[(size_t)k*U_];
    acc0 += a0p[k]*wv;
    acc1 += a1p[k]*wv;
  }
  atomicAdd(&attn_out[bh*U_+n], acc0);
  atomicAdd(&attn_out[(bh+16)*U_+n], acc1);
}

// ---------------- fp32 -> bf16 converts ----------------
__global__ void f2bf4_kernel(const float* __restrict__ in, unsigned short* __restrict__ out, int n){
  int i = (blockIdx.x*256 + threadIdx.x)*4;
  if(i < n){
    float4 v = *(const float4*)(in + i);
    unsigned p0 = (unsigned)f2bf(v.x) | ((unsigned)f2bf(v.y)<<16);
    unsigned p1 = (unsigned)f2bf(v.z) | ((unsigned)f2bf(v.w)<<16);
    uint2 r; r.x = p0; r.y = p1;
    *(uint2*)(out + i) = r;
  }
}

// Wf [1024][32000] f32 -> WfT [32000][1024] bf16, 32x32 tiles
// grid: (1000 n-tiles, 32 k-tiles), block 256
__global__ __launch_bounds__(256) void transpose_f2bf(
    const float* __restrict__ Wf, unsigned short* __restrict__ WfT)
{
  __shared__ float t[32][33];
  int n0 = blockIdx.x*32, k0 = blockIdx.y*32;
  int tid = threadIdx.x;
  int cx = tid&31, ry = tid>>5;   // 8 rows per pass
  for(int r=ry; r<32; r+=8) t[r][cx] = Wf[(size_t)(k0+r)*VT_ + n0+cx];
  __syncthreads();
  for(int r=ry; r<32; r+=8)
    WfT[(size_t)(n0+r)*1024 + k0+cx] = f2bf(t[cx][r]);
}

// ---------------- logits GEMM: bf16 MFMA 16x16x32 ----------------
// C[m][n] = attn[m][:] . Wf[:][n] + bf[n]; m = t*32+b -> out[(b*63+t)*32000+n]
// A: attn_bf [2016][1024] (row-major, k-contig); Bt: WfT [32000][1024] (k-contig)
// grid: (63 m-tiles of 32, 125 n-tiles of 256), block 256 (4 waves: 2x2 of 16m x 128n)
__global__ __launch_bounds__(256) void logits_gemm(
    const unsigned short* __restrict__ Abf, const unsigned short* __restrict__ Bt,
    const float* __restrict__ bias, float* __restrict__ out)
{
  __shared__ __align__(16) unsigned short As[32][40];
  __shared__ __align__(16) unsigned short Bs[256][40];
  int tid = threadIdx.x;
  int m0 = blockIdx.x*32, n0 = blockIdx.y*256;
  int w = tid>>6, lane = tid&63;
  int wm = w&1, wn = w>>1;
  floatx4 acc[8];
  #pragma unroll
  for(int i=0;i<8;i++) acc[i] = (floatx4)(0.f);

  int rl = lane&15, kg = lane>>4;

  for(int kt=0; kt<1024; kt+=32){
    __syncthreads();
    {
      int mm = tid>>3, kq = tid&7;
      const unsigned short* src = Abf + (size_t)(m0+mm)*1024 + kt + kq*4;
      *(uint2*)(&As[mm][kq*4]) = *(const uint2*)src;
    }
    {
      const unsigned short* bsrc = Bt + (size_t)(n0+tid)*1024 + kt;
      *(uint4*)(&Bs[tid][0])  = *(const uint4*)(bsrc);
      *(uint4*)(&Bs[tid][8])  = *(const uint4*)(bsrc+8);
      *(uint4*)(&Bs[tid][16]) = *(const uint4*)(bsrc+16);
      *(uint4*)(&Bs[tid][24]) = *(const uint4*)(bsrc+24);
    }
    __syncthreads();
    short8 afrag = *(const short8*)(&As[wm*16 + rl][kg*8]);
    #pragma unroll
    for(int nt=0; nt<8; nt++){
      short8 bfrag = *(const short8*)(&Bs[wn*128 + nt*16 + rl][kg*8]);
      acc[nt] = __builtin_amdgcn_mfma_f32_16x16x32_bf16(afrag, bfrag, acc[nt], 0,0,0);
    }
  }
  #pragma unroll
  for(int nt=0; nt<8; nt++){
    int n = n0 + wn*128 + nt*16 + rl;
    float bv = bias[n];
    #pragma unroll
    for(int r=0;r<4;r++){
      int m = m0 + wm*16 + kg*4 + r;
      int t = m>>5, b = m&31;
      out[((size_t)(b*TD_) + t)*VT_ + n] = acc[nt][r] + bv;
    }
  }
}

// ---------------- host ----------------
extern "C" void kernel_launch(void* const* d_in, const int* in_sizes, int n_in,
                              void* d_out, int out_size, void* d_ws, size_t ws_size,
                              hipStream_t stream) {
  (void)in_sizes; (void)n_in; (void)out_size; (void)ws_size;
  const int*   enc_in  = (const int*)d_in[0];
  const int*   dec_in  = (const int*)d_in[1];
  const float* enc_emb = (const float*)d_in[2];
  const float* dec_emb = (const float*)d_in[3];
  const float* Wx_e    = (const float*)d_in[4];
  const float* Wh_e    = (const float*)d_in[5];
  const float* b_e     = (const float*)d_in[6];
  const float* Wx_d    = (const float*)d_in[7];
  const float* Wh_d    = (const float*)d_in[8];
  const float* b_d     = (const float*)d_in[9];
  const float* Wm      = (const float*)d_in[10];
  const float* Wa      = (const float*)d_in[11];
  const float* Wf      = (const float*)d_in[12];
  const float* bf      = (const float*)d_in[13];
  float* out = (float*)d_out;

  float* ws = (float*)d_ws;
  size_t off = 0;
  float* Xe       = ws + off; off += (size_t)TS_*B_*G_;     // 8388608
  float* Xd       = ws + off; off += (size_t)TD_*B_*G_;     // 8257536
  float* memory   = ws + off; off += (size_t)TS_*B_*U_;     // 2097152
  float* keys     = ws + off; off += (size_t)TS_*B_*U_;     // 2097152
  float* attn_buf = ws + off; off += (size_t)64*B_*U_;      // 2097152 (slot0 = zeros)
  float* cbuf     = ws + off; off += (size_t)B_*U_;
  float* hbuf0    = ws + off; off += (size_t)B_*U_;
  float* hbuf1    = ws + off; off += (size_t)B_*U_;
  float* ctx      = ws + off; off += (size_t)B_*U_;
  unsigned short* attn_bf = (unsigned short*)(ws + off); off += (size_t)(2016*1024)/2;
  unsigned short* WfT     = (unsigned short*)(ws + off);

  // zero attn_buf + cbuf (contiguous)
  {
    int n4 = (64*B_*U_ + B_*U_)/4;   // 532480
    zero_kernel<<<(n4+255)/256, 256, 0, stream>>>((float4*)attn_buf, n4);
  }
  // encoder/decoder input pre-activations
  gemm_rows<<<dim3(G_/256, (TS_*B_)/16), 256, 0, stream>>>(enc_emb, enc_in, TS_, Wx_e, b_e, Xe, G_, E_);
  gemm_rows<<<dim3(G_/256, (TD_*B_)/16), 256, 0, stream>>>(dec_emb, dec_in, TD_, Wx_d, b_d, Xd, G_, E_);
  // Wf transpose+convert (independent of recurrence)
  transpose_f2bf<<<dim3(VT_/32, 1024/32), 256, 0, stream>>>(Wf, WfT);

  // encoder recurrence (h0 = attn_buf slot0 zeros)
  for(int t=0; t<TS_; t++){
    const float* hprev = (t==0) ? attn_buf : memory + (size_t)(t-1)*B_*U_;
    enc_step<<<U_/4, 256, 0, stream>>>(Xe + (size_t)t*B_*G_, Wh_e, hprev, cbuf,
                                       memory + (size_t)t*B_*U_);
  }
  // keys = memory @ Wm
  gemm_rows<<<dim3(U_/256, (TS_*B_)/16), 256, 0, stream>>>(memory, nullptr, 0, Wm, nullptr, keys, U_, U_);

  // decoder recurrence
  const float* mem_last = memory + (size_t)(TS_-1)*B_*U_;
  const float* Wxa = Wx_d + (size_t)E_*G_;
  for(int t=0; t<TD_; t++){
    const float* hin  = (t==0) ? mem_last : (((t-1)&1) ? hbuf1 : hbuf0);
    float* hout = (t&1) ? hbuf1 : hbuf0;
    const float* aprev = attn_buf + (size_t)t*B_*U_;
    float* anext       = attn_buf + (size_t)(t+1)*B_*U_;
    dec_step<<<U_/4, 256, 0, stream>>>(Xd + (size_t)t*B_*G_, Wh_d, Wxa, hin, aprev, cbuf, hout);
    attn_ctx<<<dim3(8, B_), 256, 0, stream>>>(hout, keys, memory, ctx);
    attn_proj<<<dim3(64, 4), 256, 0, stream>>>(hout, ctx, Wa, anext);
  }

  // logits = attn_all @ Wf + bf  (bf16 MFMA)
  {
    int n = 2016*1024;
    f2bf4_kernel<<<(n/4+255)/256, 256, 0, stream>>>(attn_buf + (size_t)B_*U_, attn_bf, n);
  }
  logits_gemm<<<dim3((TD_*B_)/32, VT_/256), 256, 0, stream>>>(attn_bf, WfT, bf, out);
}

// Round 2
// 15811.177 us; speedup vs baseline: 1.5355x; 1.5355x over previous
//
#include <hip/hip_runtime.h>
#include <hip/hip_bf16.h>

#define B_  32
#define TS_ 64
#define TD_ 63
#define E_  256
#define U_  1024
#define G_  4096   // 4*U
#define VT_ 32000

typedef __attribute__((ext_vector_type(8))) short short8;
typedef __attribute__((ext_vector_type(4))) float floatx4;

__device__ __forceinline__ float sigf(float x){ return 1.0f/(1.0f+__expf(-x)); }
__device__ __forceinline__ float tanh_fast(float x){ return 2.0f/(1.0f+__expf(-2.0f*x)) - 1.0f; }
__device__ __forceinline__ unsigned short f2bf(float x){
  unsigned u = __float_as_uint(x);
  u += 0x7FFFu + ((u>>16)&1u);
  return (unsigned short)(u>>16);
}

// ---------------- zero init ----------------
__global__ void zero_kernel(float4* __restrict__ p, int n4){
  int i = blockIdx.x*256 + threadIdx.x;
  if(i < n4) p[i] = make_float4(0.f,0.f,0.f,0.f);
}

// ---------------- generic row-gather GEMM (fp32) ----------------
// C[m][n] = bias[n] + sum_k Arow(m)[k] * Bw[k*N + n]
__global__ __launch_bounds__(256) void gemm_rows(
    const float* __restrict__ Atab, const int* __restrict__ tokens, int T,
    const float* __restrict__ Bw, const float* __restrict__ bias,
    float* __restrict__ C, int N, int K)
{
  __shared__ float as[64*20];
  int tid = threadIdx.x;
  int n  = blockIdx.x*256 + tid;
  int m0 = blockIdx.y*16;
  float acc[16];
  #pragma unroll
  for(int r=0;r<16;r++) acc[r]=0.f;

  for(int kc=0; kc<K; kc+=64){
    __syncthreads();
    for(int i=tid; i<16*64; i+=256){
      int mm = i>>6, kk = i&63;
      int m = m0 + mm;
      const float* arow;
      if(tokens){
        int b = m & 31, t = m >> 5;
        arow = Atab + (size_t)tokens[b*T + t]*K;
      } else {
        arow = Atab + (size_t)m*K;
      }
      as[kk*20 + mm] = arow[kc + kk];
    }
    __syncthreads();
    for(int kk=0; kk<64; kk++){
      float bv = Bw[(size_t)(kc+kk)*N + n];
      const float4* ap = (const float4*)(as + kk*20);
      float4 a0 = ap[0], a1 = ap[1], a2 = ap[2], a3 = ap[3];
      acc[0]  += a0.x*bv; acc[1]  += a0.y*bv; acc[2]  += a0.z*bv; acc[3]  += a0.w*bv;
      acc[4]  += a1.x*bv; acc[5]  += a1.y*bv; acc[6]  += a1.z*bv; acc[7]  += a1.w*bv;
      acc[8]  += a2.x*bv; acc[9]  += a2.y*bv; acc[10] += a2.z*bv; acc[11] += a2.w*bv;
      acc[12] += a3.x*bv; acc[13] += a3.y*bv; acc[14] += a3.z*bv; acc[15] += a3.w*bv;
    }
  }
  float bv = bias ? bias[n] : 0.f;
  #pragma unroll
  for(int r=0;r<16;r++)
    C[(size_t)(m0+r)*N + n] = acc[r] + bv;
}

// ---------------- recurrent-step split-K GEMM ----------------
// zpart[kq][m][n] = sum_{k in chunk kq} src[m][k] * W[k][n]
// K chunks of 256: kq<4 -> (W1, s1), kq>=4 -> (W2, s2), k0 = (kq&3)*256.
// grid (N/64, KQ), block 256 = 4 waves (8 m each) x 64 n. W reads coalesced
// (256B/wave); src reads are wave-uniform broadcasts (1 line/instr, L1-hit).
__global__ __launch_bounds__(256) void step_mm(
    const float* __restrict__ W1, const float* __restrict__ W2,
    const float* __restrict__ s1, const float* __restrict__ s2,
    float* __restrict__ zpart, int N)
{
  int tid = threadIdx.x;
  int nl = tid & 63, mg = tid >> 6;
  int n = blockIdx.x*64 + nl;
  int kq = blockIdx.y;
  int k0 = (kq & 3) * 256;
  const float* W  = ((kq < 4) ? W1 : W2) + (size_t)k0 * N + n;
  const float* hp = ((kq < 4) ? s1 : s2) + (size_t)(mg*8) * U_ + k0;
  float acc[8];
  #pragma unroll
  for(int i=0;i<8;i++) acc[i]=0.f;
  #pragma unroll 4
  for(int k=0; k<256; k++){
    float wv = W[(size_t)k * N];
    #pragma unroll
    for(int mi=0; mi<8; mi++)
      acc[mi] += hp[(size_t)mi*U_ + k] * wv;
  }
  float* zp = zpart + ((size_t)(kq*32 + mg*8)) * N + n;
  #pragma unroll
  for(int mi=0; mi<8; mi++)
    zp[(size_t)mi * N] = acc[mi];
}

// ---------------- gates (encoder; also generic) ----------------
// z[b][g*1024+u] = X_t + sum_p zpart ; LSTM gate update
__global__ __launch_bounds__(256) void gate_h(
    const float* __restrict__ X_t, const float* __restrict__ zpart, int KQ,
    float* __restrict__ c, float* __restrict__ hout)
{
  int i = blockIdx.x*256 + threadIdx.x;   // 0..32767
  int b = i >> 10, u = i & 1023;
  float zg[4];
  #pragma unroll
  for(int g=0; g<4; g++){
    int col = g*U_ + u;
    float s = X_t[(size_t)b*G_ + col];
    for(int p=0; p<KQ; p++) s += zpart[((size_t)(p*32+b))*G_ + col];
    zg[g] = s;
  }
  float cn = sigf(zg[1])*c[i] + sigf(zg[0])*tanh_fast(zg[2]);
  float hn = sigf(zg[3])*tanh_fast(cn);
  c[i] = cn;
  hout[i] = hn;
}

// ---------------- decoder: gates + scores + softmax + context ----------------
// one block per batch b (32 blocks, 256 threads)
__global__ __launch_bounds__(256) void dec_gate_attn(
    const float* __restrict__ Xd_t, const float* __restrict__ zpart,
    float* __restrict__ c, const float* __restrict__ keys,
    const float* __restrict__ memory, float* __restrict__ hout,
    float* __restrict__ ctx)
{
  int b = blockIdx.x;
  int tid = threadIdx.x;
  __shared__ float hs[1024];
  __shared__ float sc[64];
  __shared__ float al[64];
  #pragma unroll
  for(int uu=0; uu<4; uu++){
    int u = uu*256 + tid;
    float zg[4];
    #pragma unroll
    for(int g=0; g<4; g++){
      int col = g*U_ + u;
      float s = Xd_t[(size_t)b*G_ + col];
      #pragma unroll
      for(int p=0; p<8; p++) s += zpart[((size_t)(p*32+b))*G_ + col];
      zg[g] = s;
    }
    int ci = b*U_ + u;
    float cn = sigf(zg[1])*c[ci] + sigf(zg[0])*tanh_fast(zg[2]);
    float hn = sigf(zg[3])*tanh_fast(cn);
    c[ci] = cn;
    hs[u] = hn;
    hout[ci] = hn;
  }
  __syncthreads();
  int w = tid>>6, lane = tid&63;
  for(int si=0; si<16; si++){
    int s = w*16 + si;
    const float* kr = keys + ((size_t)s*B_ + b)*U_;
    float p = 0.f;
    for(int kk=lane; kk<1024; kk+=64) p += hs[kk]*kr[kk];
    for(int off=32; off; off>>=1) p += __shfl_down(p, off);
    if(lane==0) sc[s] = p;
  }
  __syncthreads();
  if(tid<64){
    float v = sc[tid];
    float mx = v;
    for(int off=32; off; off>>=1) mx = fmaxf(mx, __shfl_down(mx, off));
    mx = __shfl(mx, 0);
    float e = __expf(v - mx);
    float sm = e;
    for(int off=32; off; off>>=1) sm += __shfl_down(sm, off);
    sm = __shfl(sm, 0);
    al[tid] = e/sm;
  }
  __syncthreads();
  #pragma unroll
  for(int uu=0; uu<4; uu++){
    int u = uu*256 + tid;
    float a = 0.f;
    for(int s=0; s<64; s++) a += al[s]*memory[((size_t)s*B_ + b)*U_ + u];
    ctx[b*U_ + u] = a;
  }
}

// ---------------- attention-projection combine (+bf16 emit) ----------------
__global__ __launch_bounds__(256) void attn_combine(
    const float* __restrict__ apart, float* __restrict__ attn_next,
    unsigned short* __restrict__ abf)
{
  int i = blockIdx.x*256 + threadIdx.x;   // 0..32767
  float s = 0.f;
  #pragma unroll
  for(int p=0; p<8; p++) s += apart[(size_t)p*32768 + i];
  attn_next[i] = s;
  abf[i] = f2bf(s);
}

// Wf [1024][32000] f32 -> WfT [32000][1024] bf16
__global__ __launch_bounds__(256) void transpose_f2bf(
    const float* __restrict__ Wf, unsigned short* __restrict__ WfT)
{
  __shared__ float t[32][33];
  int n0 = blockIdx.x*32, k0 = blockIdx.y*32;
  int tid = threadIdx.x;
  int cx = tid&31, ry = tid>>5;
  for(int r=ry; r<32; r+=8) t[r][cx] = Wf[(size_t)(k0+r)*VT_ + n0+cx];
  __syncthreads();
  for(int r=ry; r<32; r+=8)
    WfT[(size_t)(n0+r)*1024 + k0+cx] = f2bf(t[cx][r]);
}

// ---------------- logits GEMM: bf16 MFMA 16x16x32 ----------------
__global__ __launch_bounds__(256) void logits_gemm(
    const unsigned short* __restrict__ Abf, const unsigned short* __restrict__ Bt,
    const float* __restrict__ bias, float* __restrict__ out)
{
  __shared__ __align__(16) unsigned short As[32][40];
  __shared__ __align__(16) unsigned short Bs[256][40];
  int tid = threadIdx.x;
  int m0 = blockIdx.x*32, n0 = blockIdx.y*256;
  int w = tid>>6, lane = tid&63;
  int wm = w&1, wn = w>>1;
  floatx4 acc[8];
  #pragma unroll
  for(int i=0;i<8;i++) acc[i] = (floatx4)(0.f);

  int rl = lane&15, kg = lane>>4;

  for(int kt=0; kt<1024; kt+=32){
    __syncthreads();
    {
      int mm = tid>>3, kq = tid&7;
      const unsigned short* src = Abf + (size_t)(m0+mm)*1024 + kt + kq*4;
      *(uint2*)(&As[mm][kq*4]) = *(const uint2*)src;
    }
    {
      const unsigned short* bsrc = Bt + (size_t)(n0+tid)*1024 + kt;
      *(uint4*)(&Bs[tid][0])  = *(const uint4*)(bsrc);
      *(uint4*)(&Bs[tid][8])  = *(const uint4*)(bsrc+8);
      *(uint4*)(&Bs[tid][16]) = *(const uint4*)(bsrc+16);
      *(uint4*)(&Bs[tid][24]) = *(const uint4*)(bsrc+24);
    }
    __syncthreads();
    short8 afrag = *(const short8*)(&As[wm*16 + rl][kg*8]);
    #pragma unroll
    for(int nt=0; nt<8; nt++){
      short8 bfrag = *(const short8*)(&Bs[wn*128 + nt*16 + rl][kg*8]);
      acc[nt] = __builtin_amdgcn_mfma_f32_16x16x32_bf16(afrag, bfrag, acc[nt], 0,0,0);
    }
  }
  #pragma unroll
  for(int nt=0; nt<8; nt++){
    int n = n0 + wn*128 + nt*16 + rl;
    float bv = bias[n];
    #pragma unroll
    for(int r=0;r<4;r++){
      int m = m0 + wm*16 + kg*4 + r;
      int t = m>>5, b = m&31;
      out[((size_t)(b*TD_) + t)*VT_ + n] = acc[nt][r] + bv;
    }
  }
}

// ---------------- host ----------------
extern "C" void kernel_launch(void* const* d_in, const int* in_sizes, int n_in,
                              void* d_out, int out_size, void* d_ws, size_t ws_size,
                              hipStream_t stream) {
  (void)in_sizes; (void)n_in; (void)out_size; (void)ws_size;
  const int*   enc_in  = (const int*)d_in[0];
  const int*   dec_in  = (const int*)d_in[1];
  const float* enc_emb = (const float*)d_in[2];
  const float* dec_emb = (const float*)d_in[3];
  const float* Wx_e    = (const float*)d_in[4];
  const float* Wh_e    = (const float*)d_in[5];
  const float* b_e     = (const float*)d_in[6];
  const float* Wx_d    = (const float*)d_in[7];
  const float* Wh_d    = (const float*)d_in[8];
  const float* b_d     = (const float*)d_in[9];
  const float* Wm      = (const float*)d_in[10];
  const float* Wa      = (const float*)d_in[11];
  const float* Wf      = (const float*)d_in[12];
  const float* bf      = (const float*)d_in[13];
  float* out = (float*)d_out;

  float* ws = (float*)d_ws;
  size_t off = 0;
  float* Xe       = ws + off; off += (size_t)TS_*B_*G_;     // 8388608
  float* Xd       = ws + off; off += (size_t)TD_*B_*G_;     // 8257536
  float* memory   = ws + off; off += (size_t)TS_*B_*U_;     // 2097152
  float* keys     = ws + off; off += (size_t)TS_*B_*U_;     // 2097152
  float* attn_buf = ws + off; off += (size_t)64*B_*U_;      // 2097152 (slot0 = zeros)
  float* cbuf     = ws + off; off += (size_t)B_*U_;
  float* hbuf     = ws + off; off += (size_t)B_*U_;
  float* ctx      = ws + off; off += (size_t)B_*U_;
  float* zpart    = ws + off; off += (size_t)8*B_*G_;       // 1048576
  float* apart    = ws + off; off += (size_t)8*B_*U_;       // 262144
  unsigned short* attn_bf = (unsigned short*)(ws + off); off += (size_t)(2016*1024)/2;
  unsigned short* WfT     = (unsigned short*)(ws + off);

  // zero attn slot0 + cbuf
  zero_kernel<<<32, 256, 0, stream>>>((float4*)attn_buf, (B_*U_)/4);
  zero_kernel<<<32, 256, 0, stream>>>((float4*)cbuf, (B_*U_)/4);

  // input pre-activations + Wf transpose (off the critical recurrence)
  gemm_rows<<<dim3(G_/256, (TS_*B_)/16), 256, 0, stream>>>(enc_emb, enc_in, TS_, Wx_e, b_e, Xe, G_, E_);
  gemm_rows<<<dim3(G_/256, (TD_*B_)/16), 256, 0, stream>>>(dec_emb, dec_in, TD_, Wx_d, b_d, Xd, G_, E_);
  transpose_f2bf<<<dim3(VT_/32, 1024/32), 256, 0, stream>>>(Wf, WfT);

  // encoder recurrence: z = h@Wh_e (split-K 4), then gates
  for(int t=0; t<TS_; t++){
    const float* hprev = (t==0) ? attn_buf : memory + (size_t)(t-1)*B_*U_;
    step_mm<<<dim3(G_/64, 4), 256, 0, stream>>>(Wh_e, Wh_e, hprev, hprev, zpart, G_);
    gate_h<<<128, 256, 0, stream>>>(Xe + (size_t)t*B_*G_, zpart, 4, cbuf,
                                    memory + (size_t)t*B_*U_);
  }

  // keys = memory @ Wm
  gemm_rows<<<dim3(U_/256, (TS_*B_)/16), 256, 0, stream>>>(memory, nullptr, 0, Wm, nullptr, keys, U_, U_);

  // decoder recurrence
  const float* mem_last = memory + (size_t)(TS_-1)*B_*U_;
  const float* Wxa = Wx_d + (size_t)E_*G_;
  const float* Wa2 = Wa + (size_t)U_*U_;
  for(int t=0; t<TD_; t++){
    const float* hin   = (t==0) ? mem_last : hbuf;
    const float* aprev = attn_buf + (size_t)t*B_*U_;
    float* anext       = attn_buf + (size_t)(t+1)*B_*U_;
    // z = h@Wh_d + a@Wxa (split-K 8)
    step_mm<<<dim3(G_/64, 8), 256, 0, stream>>>(Wh_d, Wxa, hin, aprev, zpart, G_);
    // gates + scores + softmax + context
    dec_gate_attn<<<B_, 256, 0, stream>>>(Xd + (size_t)t*B_*G_, zpart, cbuf,
                                          keys, memory, hbuf, ctx);
    // attn = [h|ctx] @ Wa (split-K 8)
    step_mm<<<dim3(U_/64, 8), 256, 0, stream>>>(Wa, Wa2, hbuf, ctx, apart, U_);
    attn_combine<<<128, 256, 0, stream>>>(apart, anext, attn_bf + (size_t)t*B_*U_);
  }

  // logits = attn_all @ Wf + bf  (bf16 MFMA)
  logits_gemm<<<dim3((TD_*B_)/32, VT_/256), 256, 0, stream>>>(attn_bf, WfT, bf, out);
}